// Round 4
// baseline (84.305 us; speedup 1.0000x reference)
//
#include <hip/hip_runtime.h>
#include <hip/hip_bf16.h>

// ILA layer (fp32 I/O): key = W@ft, query = W@fk (1x1 conv, shared W),
// sim[p,k] = <query[p], key[neighbor_k(p)]> over 9x9 window (zero-padded keys),
// weight = softmax_k(sim)  (OOB entries participate with sim=0),
// out[c,p] = sum_k weight[k] * ft[c, neighbor_k(p)]  (zero-padded ft).
// n=2, c=128, h=w=64, L=9 (81 neighbors).
// R22 = FULLY FUSED single kernel (was 2 kernels + 12 MB ws round-trip).
// Per 8-px strip block: stage W + ft-window(fp16, tr-tile layout xw) + fk(8px),
// project K (16x9 window, 72 MFMA/wave) and Q (8 MFMA/wave) IN-BLOCK with
// swapped operands (D[o][px] -> h4 LDS stores), write swizzled Ksw/Qsw
// (Ksw aliases dead Wth), then the verified R21 dot/softmax/weighting phases
// unchanged. xw serves both projection-A and weighting-tr16-B; no workspace.
// LDS 79632 B -> 2 blocks/CU; 5 barriers.

#define Hh 64
#define Ww 64
#define Cc 128
#define Nn 2
#define KK 81
#define HW (Hh * Ww)          // 4096
#define CHW (Cc * HW)         // 524288

#define FTL_CH 2312           // halves per c-chunk of xw (9*256 + 8 pad)

typedef _Float16 h8 __attribute__((ext_vector_type(8)));
typedef _Float16 h4 __attribute__((ext_vector_type(4)));
typedef float f4v __attribute__((ext_vector_type(4)));

#ifndef __has_builtin
#define __has_builtin(x) 0
#endif

// LDS transpose-read: lane l receives tile[quad*4+j][l&15] of a contiguous
// row-major [16][16] half tile when per-lane addr = tile_base + 8*lane bytes.
#if __has_builtin(__builtin_amdgcn_ds_read_tr16_b64_v4f16)
#define TR_BUILTIN 1
typedef __fp16 g4 __attribute__((__vector_size__(4 * sizeof(__fp16))));
static __device__ __forceinline__ h4 tr16(const _Float16* p) {
    g4 r = __builtin_amdgcn_ds_read_tr16_b64_v4f16(
        (__attribute__((address_space(3))) g4*)p);
    return __builtin_bit_cast(h4, r);
}
#else
#define TR_BUILTIN 0
static __device__ __forceinline__ h4 tr16(const _Float16* p) {
    h4 r;
    asm volatile("ds_read_b64_tr_b16 %0, %1"
                 : "=v"(r)
                 : "v"((__attribute__((address_space(3))) _Float16*)p));
    return r;
}
#endif

// LDS map (bytes):
//   [0,     36992)  xw   : ft fp16 window, tr-tile layout [chunk][r][xx][16c]
//   [36992, 71808)  Wth  : [o][i] stride 136  (dead after projection reads)
//   [36992, 73856)  Ksw  : swizzled keys (alias over Wth, written post-S2)
//   [73856, 75904)  Qsw  : swizzled queries (8 rows)
//   [75904, 77200)  simb : softmaxed weights fp16 [k][8]
//   [77200, 77328)  redM ; [77328, 77456) redS
//   [77456, 79632)  xq   : fk fp16 [8 px][136]
__global__ __launch_bounds__(256, 2) void ila_fused(const float* __restrict__ ft,
                                                    const float* __restrict__ fk,
                                                    const float* __restrict__ Wm,
                                                    float* __restrict__ out) {
    __shared__ __align__(16) unsigned char smem[79632];
    _Float16* xw   = (_Float16*)(smem);
    _Float16* Wth  = (_Float16*)(smem + 36992);
    _Float16* Ksw  = (_Float16*)(smem + 36992);
    _Float16* Qsw  = (_Float16*)(smem + 73856);
    _Float16* simb = (_Float16*)(smem + 75904);
    float*    redM = (float*)(smem + 77200);
    float*    redS = (float*)(smem + 77328);
    _Float16* xq   = (_Float16*)(smem + 77456);

    const int t  = threadIdx.x;
    const int b  = blockIdx.x;
    const int x0 = (b & 7) << 3;
    const int y  = (b >> 3) & 63;
    const int nn = b >> 9;

    // ---- stage W -> fp16 [o][i] stride 136
#pragma unroll 4
    for (int e = t; e < 4096; e += 256) {
        const int o = e >> 5, ch = e & 31;
        const float4 v = *(const float4*)&Wm[o * 128 + (ch << 2)];
        h4 hv; hv[0] = (_Float16)v.x; hv[1] = (_Float16)v.y;
               hv[2] = (_Float16)v.z; hv[3] = (_Float16)v.w;
        *(h4*)&Wth[o * 136 + (ch << 2)] = hv;
    }

    // ---- stage ft window (16x9 px, zero-padded) -> xw tr-tiles
    // element (v = r*16+xx, c) at (c>>4)*FTL_CH + r*256 + xx*16 + (c&15)
#pragma unroll
    for (int i = 0; i < 18; ++i) {
        const int e = t + (i << 8);
        const int xb = e & 3, c = (e >> 2) & 127, r = e >> 9;
        const int gx0 = x0 + (xb << 2) - 4;
        const int gy  = y + r - 4;
        float4 v = make_float4(0.f, 0.f, 0.f, 0.f);
        if ((unsigned)gx0 <= 60u && (unsigned)gy < 64u)
            v = *(const float4*)&ft[nn * CHW + c * HW + (gy << 6) + gx0];
        _Float16* base = &xw[(c >> 4) * FTL_CH + (r << 8) + (xb << 6) + (c & 15)];
        base[0]  = (_Float16)v.x;
        base[16] = (_Float16)v.y;
        base[32] = (_Float16)v.z;
        base[48] = (_Float16)v.w;
    }

    // ---- stage fk (8 px) -> xq [px][c] stride 136
    {
        const int xb = t & 1, c = t >> 1;
        const float4 v = *(const float4*)&fk[nn * CHW + c * HW + (y << 6) + x0 + (xb << 2)];
        _Float16* base = &xq[((xb << 2)) * 136 + c];
        base[0]   = (_Float16)v.x;
        base[136] = (_Float16)v.y;
        base[272] = (_Float16)v.z;
        base[408] = (_Float16)v.w;
    }
    __syncthreads();   // S1

    const int lane = t & 63, wv = t >> 6;
    const int quad = lane >> 4, l15 = lane & 15;
    const int qrow = l15 & 7;

    // ---- projection via MFMA, SWAPPED operands: D[o][px].
    // A = Wth rows o (lane row = l15), B = xw cols px (lane col = l15), k = c.
    // Wave wv owns output-channel tiles nt = 2wv, 2wv+1.
    f4v accK[9][2];
    f4v accQ[2];
#pragma unroll
    for (int pt = 0; pt < 9; ++pt) {
        accK[pt][0] = (f4v){0.f, 0.f, 0.f, 0.f};
        accK[pt][1] = (f4v){0.f, 0.f, 0.f, 0.f};
    }
    accQ[0] = (f4v){0.f, 0.f, 0.f, 0.f};
    accQ[1] = (f4v){0.f, 0.f, 0.f, 0.f};
#pragma unroll
    for (int kc = 0; kc < 4; ++kc) {
        const int c0 = (kc << 5) + (quad << 3);
        const h8 bw0 = *(const h8*)&Wth[((wv << 5) + l15) * 136 + c0];
        const h8 bw1 = *(const h8*)&Wth[((wv << 5) + 16 + l15) * 136 + c0];
        const h8 aq  = *(const h8*)&xq[qrow * 136 + c0];   // cols 8-15 dup 0-7
        accQ[0] = __builtin_amdgcn_mfma_f32_16x16x32_f16(bw0, aq, accQ[0], 0, 0, 0);
        accQ[1] = __builtin_amdgcn_mfma_f32_16x16x32_f16(bw1, aq, accQ[1], 0, 0, 0);
        const int xoff = ((c0 >> 4) * FTL_CH) + (c0 & 15);
#pragma unroll
        for (int pt = 0; pt < 9; ++pt) {
            const h8 ax = *(const h8*)&xw[xoff + (pt << 8) + (l15 << 4)];
            accK[pt][0] = __builtin_amdgcn_mfma_f32_16x16x32_f16(bw0, ax, accK[pt][0], 0, 0, 0);
            accK[pt][1] = __builtin_amdgcn_mfma_f32_16x16x32_f16(bw1, ax, accK[pt][1], 0, 0, 0);
        }
    }
    __syncthreads();   // S2: Wth/xq MFMA reads done -> Ksw/Qsw region writable

    // ---- write swizzled K/Q: element (v, o) at (v<<7)+(((o>>3)^(v&15))<<3)+(o&7).
    // Lane holds px = v-col = l15, o rows (2wv+ni)*16 + quad*4 + r -> h4 stores.
    {
        const int q4 = (quad & 1) << 2;
#pragma unroll
        for (int ni = 0; ni < 2; ++ni) {
            const int ci = ((wv << 1) + ni) * 2 + (quad >> 1);   // o>>3
#pragma unroll
            for (int pt = 0; pt < 9; ++pt) {
                const int v = (pt << 4) + l15;
                h4 hk; hk[0] = (_Float16)accK[pt][ni][0]; hk[1] = (_Float16)accK[pt][ni][1];
                       hk[2] = (_Float16)accK[pt][ni][2]; hk[3] = (_Float16)accK[pt][ni][3];
                *(h4*)&Ksw[(v << 7) + ((ci ^ l15) << 3) + q4] = hk;
            }
            if (l15 < 8) {
                h4 hq; hq[0] = (_Float16)accQ[ni][0]; hq[1] = (_Float16)accQ[ni][1];
                       hq[2] = (_Float16)accQ[ni][2]; hq[3] = (_Float16)accQ[ni][3];
                *(h4*)&Qsw[(l15 << 7) + ((ci ^ l15) << 3) + q4] = hq;
            }
        }
    }
    __syncthreads();   // S3: Ksw/Qsw complete

    // ---- dots via MFMA: per r, S_r[xx][p] = sum_c Ksw[r*16+xx][c] * Q[p][c]
    // D: row=xx=quad*4+reg, col=p=lane&15 [R13 HW-verified layout].
    h8 qb[4];
#pragma unroll
    for (int kc = 0; kc < 4; ++kc) {
        const int ci = (kc << 2) + quad;
        qb[kc] = *(const h8*)&Qsw[(qrow << 7) + ((ci ^ qrow) << 3)];
    }
    const int r0 = wv, r1 = wv + 4;           // r2 = 8 computed by all, owned by wave 0
    f4v acc0 = {0.f, 0.f, 0.f, 0.f}, acc1 = acc0, acc2 = acc0;
#pragma unroll
    for (int kc = 0; kc < 4; ++kc) {
        const int ci = (kc << 2) + quad;
        const h8 kA = *(const h8*)&Ksw[(((r0 << 4) + l15) << 7) + ((ci ^ l15) << 3)];
        const h8 kB = *(const h8*)&Ksw[(((r1 << 4) + l15) << 7) + ((ci ^ l15) << 3)];
        const h8 kC = *(const h8*)&Ksw[(((8  << 4) + l15) << 7) + ((ci ^ l15) << 3)];
        acc0 = __builtin_amdgcn_mfma_f32_16x16x32_f16(kA, qb[kc], acc0, 0, 0, 0);
        acc1 = __builtin_amdgcn_mfma_f32_16x16x32_f16(kB, qb[kc], acc1, 0, 0, 0);
        acc2 = __builtin_amdgcn_mfma_f32_16x16x32_f16(kC, qb[kc], acc2, 0, 0, 0);
    }

    // ---- in-layout softmax, phase 1: band-masked max over xx, then quads
    float m = -3.0e38f;
#pragma unroll
    for (int reg = 0; reg < 4; ++reg) {
        const int dx = (quad << 2) + reg - l15;         // xx - p
        const bool ok = (l15 < 8) && ((unsigned)dx < 9u);
        if (ok) {
            m = fmaxf(m, fmaxf(acc0[reg], acc1[reg]));
            m = fmaxf(m, acc2[reg]);
        }
    }
    m = fmaxf(m, __shfl_xor(m, 16));
    m = fmaxf(m, __shfl_xor(m, 32));
    if (quad == 0 && l15 < 8) redM[(wv << 3) + l15] = m;
    __syncthreads();   // S4: redM complete (Ksw/Qsw dead)

    // ---- B-fragments for the weighting MFMAs: 18 tr reads from xw (stable
    // since S1); latency hides under the exp phase, drained by S5.
    const _Float16* ftc0 = xw + wv * FTL_CH;
    const _Float16* ftc1 = xw + (wv + 4) * FTL_CH;
    h4 bfr[18];
#pragma unroll
    for (int r = 0; r < 9; ++r) {
        bfr[r]     = tr16(ftc0 + (r << 8) + (lane << 2));
        bfr[9 + r] = tr16(ftc1 + (r << 8) + (lane << 2));
    }

    // ---- phase 2: exp + write simb (fp16) + band-masked sum over xx, then quads
    const float mm = fmaxf(fmaxf(redM[qrow], redM[8 + qrow]),
                           fmaxf(redM[16 + qrow], redM[24 + qrow]));
    float ssum = 0.f;
#pragma unroll
    for (int reg = 0; reg < 4; ++reg) {
        const int dx = (quad << 2) + reg - l15;
        const bool ok = (l15 < 8) && ((unsigned)dx < 9u);
        const float e0 = ok ? __expf(acc0[reg] - mm) : 0.f;
        const float e1 = ok ? __expf(acc1[reg] - mm) : 0.f;
        const float e2 = (ok && wv == 0) ? __expf(acc2[reg] - mm) : 0.f;
        if (ok)            simb[((r0 * 9 + dx) << 3) + l15] = (_Float16)e0;
        if (ok)            simb[((r1 * 9 + dx) << 3) + l15] = (_Float16)e1;
        if (ok && wv == 0) simb[((8  * 9 + dx) << 3) + l15] = (_Float16)e2;
        ssum += e0 + e1 + e2;
    }
    ssum += __shfl_xor(ssum, 16);
    ssum += __shfl_xor(ssum, 32);
    if (quad == 0 && l15 < 8) redS[(wv << 3) + l15] = ssum;
    __syncthreads();   // S5: simb + redS complete; bfr tr reads drained

#if !TR_BUILTIN
    asm volatile("s_waitcnt lgkmcnt(0)");   // rule-#18 fence for asm-path bfr
    __builtin_amdgcn_sched_barrier(0);
#endif

    // ---- weighting via MFMA: per r, D[p][c] += A[p][xx] * B[xx][c]
    // A[p][xx] = simb[r*9 + (xx-p)][p] on the band 0<=xx-p<9 (rows 8-15 dup'd).
    f4v aw0 = {0.f, 0.f, 0.f, 0.f}, aw1 = aw0;
#pragma unroll
    for (int r = 0; r < 9; ++r) {
        h4 afr;
#pragma unroll
        for (int j = 0; j < 4; ++j) {
            const int dx = (quad << 2) + j - qrow;
            const bool ok = (unsigned)dx < 9u;
            afr[j] = ok ? simb[(((r * 9 + dx) << 3) + qrow)] : (_Float16)0.f;
        }
        aw0 = __builtin_amdgcn_mfma_f32_16x16x16f16(afr, bfr[r],     aw0, 0, 0, 0);
        aw1 = __builtin_amdgcn_mfma_f32_16x16x16f16(afr, bfr[9 + r], aw1, 0, 0, 0);
    }

    // D layout: row = p = quad*4+reg (quads 0-1 hold p=0..7), col = c = l15.
    if (quad < 2) {
        const int q4 = quad << 2;
        const float4 rs0 = *(const float4*)&redS[q4];
        const float4 rs1 = *(const float4*)&redS[8 + q4];
        const float4 rs2 = *(const float4*)&redS[16 + q4];
        const float4 rs3 = *(const float4*)&redS[24 + q4];
        const float iv0 = 1.f / (rs0.x + rs1.x + rs2.x + rs3.x);
        const float iv1 = 1.f / (rs0.y + rs1.y + rs2.y + rs3.y);
        const float iv2 = 1.f / (rs0.z + rs1.z + rs2.z + rs3.z);
        const float iv3 = 1.f / (rs0.w + rs1.w + rs2.w + rs3.w);
        const int xb = (y << 6) + x0 + q4;
        const size_t ob0 = ((size_t)((nn << 7) + (wv << 4) + l15) << 12) + xb;
        const size_t ob1 = ((size_t)((nn << 7) + ((wv + 4) << 4) + l15) << 12) + xb;
        float4 o0, o1;
        o0.x = aw0[0] * iv0; o0.y = aw0[1] * iv1; o0.z = aw0[2] * iv2; o0.w = aw0[3] * iv3;
        o1.x = aw1[0] * iv0; o1.y = aw1[1] * iv1; o1.z = aw1[2] * iv2; o1.w = aw1[3] * iv3;
        *(float4*)&out[ob0] = o0;
        *(float4*)&out[ob1] = o1;
    }
}

extern "C" void kernel_launch(void* const* d_in, const int* in_sizes, int n_in,
                              void* d_out, int out_size, void* d_ws, size_t ws_size,
                              hipStream_t stream) {
    const float* ft = (const float*)d_in[0];
    const float* fk = (const float*)d_in[1];
    const float* Wm = (const float*)d_in[2];
    float* out = (float*)d_out;
    (void)d_ws; (void)ws_size;

    ila_fused<<<1024, 256, 0, stream>>>(ft, fk, Wm, out);
}

// Round 5
// 76.196 us; speedup vs baseline: 1.1064x; 1.1064x over previous
//
#include <hip/hip_runtime.h>
#include <hip/hip_bf16.h>

// ILA layer (fp32 I/O): key = W@ft, query = W@fk (1x1 conv, shared W),
// sim[p,k] = <query[p], key[neighbor_k(p)]> over 9x9 window (zero-padded keys),
// weight = softmax_k(sim)  (OOB entries participate with sim=0),
// out[c,p] = sum_k weight[k] * ft[c, neighbor_k(p)]  (zero-padded ft).
// n=2, c=128, h=w=64, L=9 (81 neighbors).
// R23 = revert R22 fusion (84.3, WORSE); back to two kernels (R21 = 76.8) with
// kernel B retiled: 2-row x 8-col output tile (16 px/block, 512 blocks).
//  - window 10x16 px for 16 outputs: stage redundancy 18x -> 10x
//  - dot MFMA N-dim fully used: p = l15 covers 16 REAL pixels (no dup half)
//  - 16 dot MFMA + 20 weighting MFMA per wave serve 16 px (was 12+18 for 8)
//  - Qsw staging deleted: Q read per-lane from L2-resident Qbuf
//  - LDS 44.2 KB -> 3 blocks/CU; same 3-barrier skeleton, same swizzles.

#define Hh 64
#define Ww 64
#define Cc 128
#define Nn 2
#define HW (Hh * Ww)          // 4096
#define CHW (Cc * HW)         // 524288

typedef _Float16 h8 __attribute__((ext_vector_type(8)));
typedef _Float16 h4 __attribute__((ext_vector_type(4)));
typedef float f4v __attribute__((ext_vector_type(4)));

#ifndef __has_builtin
#define __has_builtin(x) 0
#endif

// LDS transpose-read: lane l receives tile[quad*4+j][l&15] of a contiguous
// row-major [16][16] half tile when per-lane addr = tile_base + 8*lane bytes.
#if __has_builtin(__builtin_amdgcn_ds_read_tr16_b64_v4f16)
#define TR_BUILTIN 1
typedef __fp16 g4 __attribute__((__vector_size__(4 * sizeof(__fp16))));
static __device__ __forceinline__ h4 tr16(const _Float16* p) {
    g4 r = __builtin_amdgcn_ds_read_tr16_b64_v4f16(
        (__attribute__((address_space(3))) g4*)p);
    return __builtin_bit_cast(h4, r);
}
#else
#define TR_BUILTIN 0
static __device__ __forceinline__ h4 tr16(const _Float16* p) {
    h4 r;
    asm volatile("ds_read_b64_tr_b16 %0, %1"
                 : "=v"(r)
                 : "v"((__attribute__((address_space(3))) _Float16*)p));
    return r;
}
#endif

// ---------------- Kernel A: projection via MFMA. 512 blocks x 16 px (unchanged R21).
__global__ __launch_bounds__(256) void proj_kernel(const float* __restrict__ ft,
                                                   const float* __restrict__ fk,
                                                   const float* __restrict__ Wm,
                                                   _Float16* __restrict__ Qbuf,
                                                   _Float16* __restrict__ Kbuf,
                                                   _Float16* __restrict__ fth) {
    __shared__ __align__(16) _Float16 Wth[128 * 136];  // [o][i] fp16 (== B[k][n] view)
    __shared__ __align__(16) _Float16 xkh[16 * 136];   // [px][c] fp16
    __shared__ __align__(16) _Float16 xqh[16 * 136];
    const int t = threadIdx.x;
    const int p0 = blockIdx.x * 16;       // 4096 % 16 == 0: never crosses n
    const int nn = p0 >> 12;
    const int gbase = nn * CHW + (p0 & 4095);

#pragma unroll 4
    for (int e = t; e < 4096; e += 256) {             // stage W -> fp16
        const int n = e >> 5, ch = e & 31;
        const float4 v = *(const float4*)&Wm[n * 128 + (ch << 2)];
        h4 hv; hv[0] = (_Float16)v.x; hv[1] = (_Float16)v.y;
               hv[2] = (_Float16)v.z; hv[3] = (_Float16)v.w;
        *(h4*)&Wth[n * 136 + (ch << 2)] = hv;
    }
#pragma unroll
    for (int e = t; e < 512; e += 256) {              // stage x -> fp16 px-major (16 px)
        const int c = e >> 2, pc = e & 3;
        const float4 vk = *(const float4*)&ft[gbase + c * HW + (pc << 2)];
        const float4 vq = *(const float4*)&fk[gbase + c * HW + (pc << 2)];
        const int px = pc << 2;
        xkh[(px    ) * 136 + c] = (_Float16)vk.x;
        xkh[(px + 1) * 136 + c] = (_Float16)vk.y;
        xkh[(px + 2) * 136 + c] = (_Float16)vk.z;
        xkh[(px + 3) * 136 + c] = (_Float16)vk.w;
        xqh[(px    ) * 136 + c] = (_Float16)vq.x;
        xqh[(px + 1) * 136 + c] = (_Float16)vq.y;
        xqh[(px + 2) * 136 + c] = (_Float16)vq.z;
        xqh[(px + 3) * 136 + c] = (_Float16)vq.w;
    }
    __syncthreads();

    {                                                 // fth: coalesced h8 copies (256 e)
        const int px = t >> 4, cq = t & 15;
        *(h8*)&fth[(size_t)(p0 + px) * 128 + (cq << 3)] =
            *(const h8*)&xkh[px * 136 + (cq << 3)];
    }

    const int lane = t & 63, wv = t >> 6;
    const int quad = lane >> 4, l15 = lane & 15;
    const _Float16* xs = (wv >> 1) ? xqh : xkh;
    _Float16* dst = (wv >> 1) ? Qbuf : Kbuf;
    const int nt0 = (wv & 1) << 2;                    // waves split the 8 nt tiles
    const int abase = l15 * 136 + (quad << 3);
    const h8 a0 = *(const h8*)&xs[abase];
    const h8 a1 = *(const h8*)&xs[abase + 32];
    const h8 a2 = *(const h8*)&xs[abase + 64];
    const h8 a3 = *(const h8*)&xs[abase + 96];
#pragma unroll
    for (int ni = 0; ni < 4; ++ni) {
        const int nt = nt0 + ni;
        const int bbase = (nt * 16 + l15) * 136 + (quad << 3);
        const h8 b0 = *(const h8*)&Wth[bbase];
        const h8 b1 = *(const h8*)&Wth[bbase + 32];
        const h8 b2 = *(const h8*)&Wth[bbase + 64];
        const h8 b3 = *(const h8*)&Wth[bbase + 96];
        f4v acc = {0.f, 0.f, 0.f, 0.f};
        acc = __builtin_amdgcn_mfma_f32_16x16x32_f16(a0, b0, acc, 0, 0, 0);
        acc = __builtin_amdgcn_mfma_f32_16x16x32_f16(a1, b1, acc, 0, 0, 0);
        acc = __builtin_amdgcn_mfma_f32_16x16x32_f16(a2, b2, acc, 0, 0, 0);
        acc = __builtin_amdgcn_mfma_f32_16x16x32_f16(a3, b3, acc, 0, 0, 0);
        const int col = nt * 16 + l15;
        const size_t rb = (size_t)(p0 + (quad << 2)) * 128 + col;
#pragma unroll
        for (int r = 0; r < 4; ++r)
            dst[rb + (size_t)r * 128] = (_Float16)acc[r];
    }
}

// ---------------- Kernel B: 16-px (2x8) tile. Window = 10 rows x 16 cols.
// Ksw swizzle: (v<<7) + ((ci ^ (v&15))<<3) halves, v = r*16+xx in [0,160).
// ftl (aliases Ksw after B2): 8 c-chunks x 2568 halves, tile r at chunk*2568+r*256.
#define FTL2 2568
__global__ __launch_bounds__(256, 3) void sim_weight_kernel(const _Float16* __restrict__ Qbuf,
                                                            const _Float16* __restrict__ Kbuf,
                                                            const _Float16* __restrict__ fth,
                                                            float* __restrict__ out) {
    __shared__ __align__(16) unsigned char smem[44192];
    _Float16* Ksw  = (_Float16*)smem;             // [0, 40960)
    _Float16* ftl  = (_Float16*)smem;             // [0, 41088) — written post-B2
    _Float16* simb = (_Float16*)(smem + 41088);   // 81*16 halves [41088, 43680)
    float*    redM = (float*)(smem + 43680);      // 64 floats [wv][p16]
    float*    redS = (float*)(smem + 43936);      // 64 floats [wv][p16]

    const int t  = threadIdx.x;
    const int b  = blockIdx.x;
    const int x0 = (b & 7) << 3;
    const int y0 = ((b >> 3) & 31) << 1;
    const int nn = b >> 8;

    // ---- stage K: zero-padded 10x16 window, h8 copies, XOR-swizzled slots
#pragma unroll
    for (int i = 0; i < 10; ++i) {
        const int e = t + (i << 8);               // 160*16 == 2560 == 10*256
        const int v = e >> 4, ci = e & 15;
        const int gx = x0 + (v & 15) - 4;
        const int gy = y0 + (v >> 4) - 4;
        h8 val = {0, 0, 0, 0, 0, 0, 0, 0};
        if ((unsigned)gx < 64u && (unsigned)gy < 64u)
            val = *(const h8*)&Kbuf[(size_t)((nn << 12) + (gy << 6) + gx) * 128 + (ci << 3)];
        *(h8*)&Ksw[(v << 7) + ((ci ^ (v & 15)) << 3)] = val;
    }
    __syncthreads();   // B1

    // ---- PREFETCH ftl source data into registers: overlaps the whole dot phase
    h8 pf[10];
#pragma unroll
    for (int i = 0; i < 10; ++i) {
        const int e = t + (i << 8);
        const int v = e >> 4, ci = e & 15;
        const int gx = x0 + (v & 15) - 4;
        const int gy = y0 + (v >> 4) - 4;
        h8 val = {0, 0, 0, 0, 0, 0, 0, 0};
        if ((unsigned)gx < 64u && (unsigned)gy < 64u)
            val = *(const h8*)&fth[(size_t)((nn << 12) + (gy << 6) + gx) * 128 + (ci << 3)];
        pf[i] = val;
    }

    // ---- dots via MFMA: per window-row r, S_r[xx][p] = sum_c K[r*16+xx][c]*Q[p][c]
    // Wave wv: rows {wv, wv+4, 8, 9} (rows 8,9 owned by waves 0,1 resp.).
    // p = l15 = 16 REAL pixels: (py = l15>>3, px = l15&7). Q direct from global.
    const int lane = t & 63, wv = t >> 6;
    const int quad = lane >> 4, l15 = lane & 15;
    const int py = l15 >> 3, px = l15 & 7;
    const size_t pgQ = (size_t)((nn << 12) + ((y0 + py) << 6) + x0 + px) * 128;
    f4v sa = {0.f, 0.f, 0.f, 0.f}, sb = sa, sc = sa, sd = sa;
#pragma unroll
    for (int kc = 0; kc < 4; ++kc) {
        const int ci = (kc << 2) + quad;
        const h8 q  = *(const h8*)&Qbuf[pgQ + (ci << 3)];
        const h8 kA = *(const h8*)&Ksw[((((wv    ) << 4) + l15) << 7) + ((ci ^ l15) << 3)];
        const h8 kB = *(const h8*)&Ksw[((((wv + 4) << 4) + l15) << 7) + ((ci ^ l15) << 3)];
        const h8 kC = *(const h8*)&Ksw[((((8     ) << 4) + l15) << 7) + ((ci ^ l15) << 3)];
        const h8 kD = *(const h8*)&Ksw[((((9     ) << 4) + l15) << 7) + ((ci ^ l15) << 3)];
        sa = __builtin_amdgcn_mfma_f32_16x16x32_f16(kA, q, sa, 0, 0, 0);
        sb = __builtin_amdgcn_mfma_f32_16x16x32_f16(kB, q, sb, 0, 0, 0);
        sc = __builtin_amdgcn_mfma_f32_16x16x32_f16(kC, q, sc, 0, 0, 0);
        sd = __builtin_amdgcn_mfma_f32_16x16x32_f16(kD, q, sd, 0, 0, 0);
    }

    // ---- in-layout softmax, phase 1: band-masked max. D: row xx=quad*4+reg, col p=l15.
    // validity: dx = xx-px in [0,9) AND ry = r-py in [0,9).
    float m = -3.0e38f;
#pragma unroll
    for (int reg = 0; reg < 4; ++reg) {
        const int dx = (quad << 2) + reg - px;
        if ((unsigned)dx < 9u) {
            if ((unsigned)(wv - py) < 9u) m = fmaxf(m, sa[reg]);  // r=wv
            m = fmaxf(m, sb[reg]);                                // r=wv+4: ry in [3,8) ok
            m = fmaxf(m, sc[reg]);                                // r=8: ry in {7,8} ok
            if (py) m = fmaxf(m, sd[reg]);                        // r=9: ry=8 only for py=1
        }
    }
    m = fmaxf(m, __shfl_xor(m, 16));
    m = fmaxf(m, __shfl_xor(m, 32));
    if (quad == 0) redM[(wv << 4) + l15] = m;
    __syncthreads();   // B2: dots' Ksw reads done; redM complete; ftl may overwrite

    // ---- restage ft from PREFETCHED registers into [chunk][r][xx][16c] tiles
#pragma unroll
    for (int i = 0; i < 10; ++i) {
        const int e = t + (i << 8);
        const int v = e >> 4, ci = e & 15;
        *(h8*)&ftl[(ci >> 1) * FTL2 + (v << 4) + ((ci & 1) << 3)] = pf[i];
    }

    // ---- phase 2: exp + write simb (fp16, [k81][p16]) + band-masked sum
    const float mm = fmaxf(fmaxf(redM[l15], redM[16 + l15]),
                           fmaxf(redM[32 + l15], redM[48 + l15]));
    float ssum = 0.f;
#pragma unroll
    for (int reg = 0; reg < 4; ++reg) {
        const int dx = (quad << 2) + reg - px;
        const bool okx = (unsigned)dx < 9u;
        {   // r = wv (unique owner)
            const int ry = wv - py;
            const bool ok = okx && ((unsigned)ry < 9u);
            const float e = ok ? __expf(sa[reg] - mm) : 0.f;
            if (ok) simb[((ry * 9 + dx) << 4) + l15] = (_Float16)e;
            ssum += e;
        }
        {   // r = wv+4 (unique owner, ry always valid)
            const int ry = wv + 4 - py;
            const float e = okx ? __expf(sb[reg] - mm) : 0.f;
            if (okx) simb[((ry * 9 + dx) << 4) + l15] = (_Float16)e;
            ssum += e;
        }
        {   // r = 8, owner wave 0
            const int ry = 8 - py;
            const bool ok = okx && (wv == 0);
            const float e = ok ? __expf(sc[reg] - mm) : 0.f;
            if (ok) simb[((ry * 9 + dx) << 4) + l15] = (_Float16)e;
            ssum += e;
        }
        {   // r = 9, owner wave 1, valid only for py=1 (ry=8)
            const bool ok = okx && (wv == 1) && (py == 1);
            const float e = ok ? __expf(sd[reg] - mm) : 0.f;
            if (ok) simb[((8 * 9 + dx) << 4) + l15] = (_Float16)e;
            ssum += e;
        }
    }
    ssum += __shfl_xor(ssum, 16);
    ssum += __shfl_xor(ssum, 32);
    if (quad == 0) redS[(wv << 4) + l15] = ssum;
    __syncthreads();   // B3: ftl + simb + redS complete

    // ---- B-fragments for the weighting MFMAs: 20 tr reads (chunks wv, wv+4)
    const _Float16* ftc0 = ftl + wv * FTL2;
    const _Float16* ftc1 = ftl + (wv + 4) * FTL2;
    h4 bfr[20];
#pragma unroll
    for (int r = 0; r < 10; ++r) {
        bfr[r]      = tr16(ftc0 + (r << 8) + (lane << 2));
        bfr[10 + r] = tr16(ftc1 + (r << 8) + (lane << 2));
    }

#if !TR_BUILTIN
    asm volatile("s_waitcnt lgkmcnt(0)");   // rule-#18 fence for asm-path bfr
    __builtin_amdgcn_sched_barrier(0);
#endif

    // ---- weighting via MFMA: per window-row r, D[p][c] += A[p][xx] * B_r[xx][c]
    // A[p][xx] = simb[(r-py)*9 + (xx-px)][p] on the band; A-frag row = l15 = p.
    f4v aw0 = {0.f, 0.f, 0.f, 0.f}, aw1 = aw0;
#pragma unroll
    for (int r = 0; r < 10; ++r) {
        const int ry = r - py;
        const bool okr = (unsigned)ry < 9u;
        h4 afr;
#pragma unroll
        for (int j = 0; j < 4; ++j) {
            const int dx = (quad << 2) + j - px;
            const bool ok = okr && ((unsigned)dx < 9u);
            afr[j] = ok ? simb[(((ry * 9 + dx) << 4)) + l15] : (_Float16)0.f;
        }
        aw0 = __builtin_amdgcn_mfma_f32_16x16x16f16(afr, bfr[r],      aw0, 0, 0, 0);
        aw1 = __builtin_amdgcn_mfma_f32_16x16x16f16(afr, bfr[10 + r], aw1, 0, 0, 0);
    }

    // D layout: row = p = quad*4+reg (16 real px), col = c-in-chunk = l15.
    // quad -> (row py0 = quad>>1, x-segment (quad&1)*4): 4 consecutive x per lane.
    {
        const int p0q = quad << 2;
        const float iv0 = 1.f / (redS[p0q    ] + redS[16 + p0q    ] + redS[32 + p0q    ] + redS[48 + p0q    ]);
        const float iv1 = 1.f / (redS[p0q + 1] + redS[16 + p0q + 1] + redS[32 + p0q + 1] + redS[48 + p0q + 1]);
        const float iv2 = 1.f / (redS[p0q + 2] + redS[16 + p0q + 2] + redS[32 + p0q + 2] + redS[48 + p0q + 2]);
        const float iv3 = 1.f / (redS[p0q + 3] + redS[16 + p0q + 3] + redS[32 + p0q + 3] + redS[48 + p0q + 3]);
        const int yo = y0 + (p0q >> 3);
        const int xb = (yo << 6) + x0 + (p0q & 7);
        const int c0 = (wv << 4) + l15;
        const int c1 = ((wv + 4) << 4) + l15;
        const size_t ob0 = ((size_t)((nn << 7) + c0) << 12) + xb;
        const size_t ob1 = ((size_t)((nn << 7) + c1) << 12) + xb;
        float4 o0, o1;
        o0.x = aw0[0] * iv0; o0.y = aw0[1] * iv1; o0.z = aw0[2] * iv2; o0.w = aw0[3] * iv3;
        o1.x = aw1[0] * iv0; o1.y = aw1[1] * iv1; o1.z = aw1[2] * iv2; o1.w = aw1[3] * iv3;
        *(float4*)&out[ob0] = o0;
        *(float4*)&out[ob1] = o1;
    }
}

extern "C" void kernel_launch(void* const* d_in, const int* in_sizes, int n_in,
                              void* d_out, int out_size, void* d_ws, size_t ws_size,
                              hipStream_t stream) {
    const float* ft = (const float*)d_in[0];
    const float* fk = (const float*)d_in[1];
    const float* Wm = (const float*)d_in[2];
    float* out = (float*)d_out;

    _Float16* wsh  = (_Float16*)d_ws;    // 6 MB: Qh(2MB) + Kh(2MB) + fth(2MB)
    _Float16* Qbuf = wsh;                // [p][c]  8192*128 halves
    _Float16* Kbuf = wsh + 1048576;      // [p][c]  8192*128 halves
    _Float16* fth  = wsh + 2097152;      // fp16 ft, PIXEL-MAJOR [p][c]

    proj_kernel<<<512, 256, 0, stream>>>(ft, fk, Wm, Qbuf, Kbuf, fth);
    sim_weight_kernel<<<512, 256, 0, stream>>>(Qbuf, Kbuf, fth, out);
}